// Round 13
// baseline (1860.595 us; speedup 1.0000x reference)
//
#include <hip/hip_runtime.h>
#include <cmath>

// R13: wavefront LSTM, role-split redesign.
//  - Gate-aligned B packing: wave-group tiles are (gate g, unit-group) so each
//    h-thread owns all 4 gates of its (row, unit) pairs -> act + c/h update
//    fully IN-THREAD. gl[] LDS round trip (and its 4.8e7 bank conflicts) gone.
//  - Role split: waves 0-6 (h): h-part MFMA + act + update + publish.
//    waves 7-13 (x): ring verify/install + x-part MFMA -> accx via LDS buffer.
//    Ring polls land on x-waves (slack) -> off the critical path.
//  - 2 barriers/step. Ring = tagged u32 (tag16|f16). RETRACTED R12 spill
//    theory: unified VGPR/AGPR file holds weights fine (VGPR_Count = arch only).

namespace {
constexpr int H = 106, SEQ = 512, BB = 256, KIN0 = 100;
constexpr int NTHR = 896, RGN = 16, NLAYER = 11, RD = 16, RROW = 112;
constexpr size_t CNT_STRIDE = 16;
constexpr size_t RING_OFF_B = 65536;
constexpr size_t RING_PER_L = (size_t)RD * BB * RROW;   // u32 elements

using f16x8 = __attribute__((ext_vector_type(8))) _Float16;
using f32x4 = __attribute__((ext_vector_type(4))) float;

__device__ __forceinline__ unsigned aldu(const unsigned* p) {
    return __hip_atomic_load(p, __ATOMIC_RELAXED, __HIP_MEMORY_SCOPE_AGENT);
}
__device__ __forceinline__ void astu(unsigned* p, unsigned v) {
    __hip_atomic_store(p, v, __ATOMIC_RELAXED, __HIP_MEMORY_SCOPE_AGENT);
}
__device__ __forceinline__ void spinc(const unsigned* p, unsigned tgt) {
    while (aldu(p) < tgt) __builtin_amdgcn_s_sleep(8);
}
__device__ __forceinline__ float fexp2(float x) {
#if __has_builtin(__builtin_amdgcn_exp2f)
    return __builtin_amdgcn_exp2f(x);
#else
    return __expf(x * 0.6931471806f);
#endif
}
__device__ __forceinline__ float frcp(float x) {
#if __has_builtin(__builtin_amdgcn_rcpf)
    return __builtin_amdgcn_rcpf(x);
#else
    return 1.0f / x;
#endif
}
__device__ __forceinline__ float fsig(float x) {
    return frcp(1.0f + fexp2(-1.44269504f * x));
}
__device__ __forceinline__ float ftanh(float x) {
    return fmaf(2.0f, frcp(1.0f + fexp2(-2.88539008f * x)), -1.0f);
}

__global__ __launch_bounds__(NTHR, 3)
void lstm_wave(const float* __restrict__ noise,   // (512,256,100) f32
               float* __restrict__ yout,          // (512,256,106) f32
               unsigned* cnt, unsigned* ring,
               const float* __restrict__ W_ih0, const float* __restrict__ W_hh0,
               const float* __restrict__ b_ih0, const float* __restrict__ b_hh0,
               const float* __restrict__ W_ih,  const float* __restrict__ W_hh,
               const float* __restrict__ b_ih,  const float* __restrict__ b_hh)
{
    const int l = blockIdx.x / RGN;
    const int rg = blockIdx.x % RGN;
    const bool LAST = (l == NLAYER - 1);
    const int K_IN = (l == 0) ? KIN0 : H;

    const float* Wih = (l == 0) ? W_ih0 : W_ih + (size_t)(l - 1) * 4 * H * H;
    const float* Whh = (l == 0) ? W_hh0 : W_hh + (size_t)(l - 1) * 4 * H * H;
    const float* pbi = (l == 0) ? b_ih0 : b_ih + (size_t)(l - 1) * 4 * H;
    const float* pbh = (l == 0) ? b_hh0 : b_hh + (size_t)(l - 1) * 4 * H;

    unsigned* cons_my = cnt + (size_t)(l * RGN + rg) * CNT_STRIDE;
    unsigned* cons_in = cnt + (size_t)((l - 1) * RGN + rg) * CNT_STRIDE;
    unsigned* ring_in  = ring + (size_t)(l - 1) * RING_PER_L;
    unsigned* ring_out = ring + (size_t)l * RING_PER_L;

    // LDS: accx handoff (20 dw/thread, 16B-aligned, bank-spread), x dbuf, h.
    __shared__ __align__(16) float axb[2][448 * 20];      // 71.7 KB
    __shared__ __align__(16) _Float16 sx[2][16 * 136];    //  8.7 KB
    __shared__ __align__(16) _Float16 sh[16 * 136];       //  4.4 KB

    const int tid = threadIdx.x;
    const int wid = tid >> 6, lane = tid & 63;
    const int l16 = lane & 15, kg = lane >> 4;
    const bool hrole = (wid < 7);
    const int wg = hrole ? wid : wid - 7;     // unit-group 0..6
    const int jh = 16 * wg + l16;             // hidden unit 0..111
    const bool jvalid = (jh < H);

    // ---- weights: 4 gate-tiles (g = i,f,g,o) x 4 k-steps, role-split ----
    f16x8 bf[4][4];
    float bias[4] = {0.f, 0.f, 0.f, 0.f};
    #pragma unroll
    for (int g = 0; g < 4; ++g) {
        const int n = g * H + (jvalid ? jh : 0);
        const float* pw = hrole ? (Whh + (size_t)n * H) : (Wih + (size_t)n * K_IN);
        const int kmax = hrole ? H : K_IN;
        #pragma unroll
        for (int q = 0; q < 4; ++q) {
            f16x8 v;
            #pragma unroll
            for (int e = 0; e < 8; ++e) {
                const int k = 32 * q + 8 * kg + e;
                v[e] = (_Float16)((jvalid && k < kmax) ? pw[k] : 0.0f);
            }
            bf[g][q] = v;
        }
        if (hrole && jvalid) bias[g] = pbi[n] + pbh[n];
    }

    // ---- zero sx (both slots) + sh ----
    for (int i = tid; i < 2 * 1088 + 1088; i += NTHR) {
        if (i < 2 * 1088) ((unsigned*)sx)[i] = 0;
        else ((unsigned*)sh)[i - 2 * 1088] = 0;
    }
    float c[4] = {0.f, 0.f, 0.f, 0.f};

    // x-side install map: element e -> (m, col)
    int m_[4], col_[4];
    const unsigned* pb_[4];        // ring base per element (l>0)
    const float* nb_[4];           // noise base per element (l==0)
    if (!hrole) {
        #pragma unroll
        for (int e = 0; e < 4; ++e) {
            const int flat = (tid - 448) + 448 * e;
            m_[e] = flat / RROW;
            col_[e] = flat % RROW;
            pb_[e] = ring_in + (size_t)(rg * 16 + m_[e]) * RROW + col_[e];
            nb_[e] = noise + (size_t)(rg * 16 + m_[e]) * 100 + col_[e];
        }
    }
    __syncthreads();

    // ---- prelude: obtain x_0, install slot 0 ----
    if (!hrole) {
        #pragma unroll
        for (int e = 0; e < 4; ++e) {
            _Float16 val = (_Float16)0.0f;
            if (l == 0) {
                if (col_[e] < 100) val = (_Float16)nb_[e][0];
            } else if (col_[e] < H) {
                unsigned v = aldu(pb_[e]);   // slot 0
                while ((v >> 16) != 1u) { __builtin_amdgcn_s_sleep(1); v = aldu(pb_[e]); }
                val = __builtin_bit_cast(_Float16, (unsigned short)(v & 0xffffu));
            }
            sx[0][m_[e] * 136 + col_[e]] = val;
        }
    }
    __syncthreads();

    // ---- prelude: accx(0) -> axb[0]; prefetch x_1 ----
    unsigned vcur[4] = {0, 0, 0, 0};
    float npre[4] = {0.f, 0.f, 0.f, 0.f};
    if (!hrole) {
        f32x4 ax[4] = {{0,0,0,0},{0,0,0,0},{0,0,0,0},{0,0,0,0}};
        const _Float16* ar = &sx[0][l16 * 136 + 8 * kg];
        #pragma unroll
        for (int q = 0; q < 4; ++q) {
            const f16x8 a = *(const f16x8*)(ar + 32 * q);
            #pragma unroll
            for (int g = 0; g < 4; ++g)
                ax[g] = __builtin_amdgcn_mfma_f32_16x16x32_f16(a, bf[g][q], ax[g], 0, 0, 0);
        }
        float* ab = &axb[0][(tid - 448) * 20];
        #pragma unroll
        for (int g = 0; g < 4; ++g) *(f32x4*)(ab + 4 * g) = ax[g];
        // prefetch x_1
        #pragma unroll
        for (int e = 0; e < 4; ++e) {
            if (l == 0) { if (col_[e] < 100) npre[e] = nb_[e][(size_t)1 * BB * 100]; }
            else if (col_[e] < H) vcur[e] = aldu(pb_[e] + ((size_t)(1 & (RD - 1)) * BB * RROW));
        }
    }
    __syncthreads();

    for (int s = 0; s < SEQ; ++s) {
        const bool wantx = (s + 1 < SEQ);
        if (!hrole) {
            // producer backpressure (one x-thread; hidden under h phase E)
            if (tid == 512 && !LAST && s >= RD && (s & 7) == 0)
                spinc(cons_my, (unsigned)(s - 6));
            // verify + install x_{s+1} into sx[(s+1)&1]
            if (wantx) {
                #pragma unroll
                for (int e = 0; e < 4; ++e) {
                    _Float16 val = (_Float16)0.0f;
                    if (l == 0) {
                        if (col_[e] < 100) val = (_Float16)npre[e];
                    } else if (col_[e] < H) {
                        const unsigned expt = (unsigned)(s + 2);
                        unsigned v = vcur[e];
                        const unsigned* pin = pb_[e] + ((size_t)((s + 1) & (RD - 1)) * BB * RROW);
                        while ((v >> 16) != expt) { __builtin_amdgcn_s_sleep(1); v = aldu(pin); }
                        val = __builtin_bit_cast(_Float16, (unsigned short)(v & 0xffffu));
                    }
                    sx[(s + 1) & 1][m_[e] * 136 + col_[e]] = val;
                }
            }
        } else {
            // phase E: acc = accx(s) + Whh . h_{s-1}
            f32x4 acc[4];
            const float* ab = &axb[s & 1][tid * 20];
            #pragma unroll
            for (int g = 0; g < 4; ++g) acc[g] = *(const f32x4*)(ab + 4 * g);
            const _Float16* ar = &sh[l16 * 136 + 8 * kg];
            #pragma unroll
            for (int q = 0; q < 4; ++q) {
                const f16x8 a = *(const f16x8*)(ar + 32 * q);
                #pragma unroll
                for (int g = 0; g < 4; ++g)
                    acc[g] = __builtin_amdgcn_mfma_f32_16x16x32_f16(a, bf[g][q], acc[g], 0, 0, 0);
            }
            // act + update, fully in-thread (gate g uniform per iteration)
            float ga[4][4];
            #pragma unroll
            for (int g = 0; g < 4; ++g)
                #pragma unroll
                for (int r = 0; r < 4; ++r) {
                    const float v = acc[g][r] + bias[g];
                    ga[g][r] = (g == 2) ? ftanh(v) : fsig(v);
                }
            #pragma unroll
            for (int r = 0; r < 4; ++r) {
                c[r] = fmaf(ga[1][r], c[r], ga[0][r] * ga[2][r]);
                const float hv = ga[3][r] * ftanh(c[r]);
                const _Float16 h16 = (_Float16)hv;
                // stash into registers; writes happen after B1
                ga[0][r] = hv;
                ga[1][r] = __builtin_bit_cast(unsigned short, h16) * 1.0f;  // keep bits
                ga[2][r] = 0.f;
                (void)h16;
            }
            __syncthreads();   // B1 (h side): sh reads done block-wide
            #pragma unroll
            for (int r = 0; r < 4; ++r) {
                const float hv = ga[0][r];
                const _Float16 h16 = (_Float16)hv;
                sh[(4 * kg + r) * 136 + jh] = h16;   // jh>=106 writes exact 0
                if (jvalid) {
                    if (LAST) {
                        yout[((size_t)s * BB + rg * 16 + 4 * kg + r) * H + jh] = hv;
                    } else {
                        astu(ring_out + (size_t)(s & (RD - 1)) * BB * RROW
                                      + (size_t)(rg * 16 + 4 * kg + r) * RROW + jh,
                             ((unsigned)(s + 1) << 16) |
                             (unsigned)__builtin_bit_cast(unsigned short, h16));
                    }
                }
            }
            goto after_b1;
        }
        __syncthreads();   // B1 (x side)
after_b1:
        if (!hrole) {
            if (wantx) {
                // phase I: accx(s+1) from sx[(s+1)&1]
                f32x4 ax[4] = {{0,0,0,0},{0,0,0,0},{0,0,0,0},{0,0,0,0}};
                const _Float16* ar = &sx[(s + 1) & 1][l16 * 136 + 8 * kg];
                #pragma unroll
                for (int q = 0; q < 4; ++q) {
                    const f16x8 a = *(const f16x8*)(ar + 32 * q);
                    #pragma unroll
                    for (int g = 0; g < 4; ++g)
                        ax[g] = __builtin_amdgcn_mfma_f32_16x16x32_f16(a, bf[g][q], ax[g], 0, 0, 0);
                }
                float* ab = &axb[(s + 1) & 1][(tid - 448) * 20];
                #pragma unroll
                for (int g = 0; g < 4; ++g) *(f32x4*)(ab + 4 * g) = ax[g];
                // prefetch x_{s+2}
                if (s + 2 < SEQ) {
                    #pragma unroll
                    for (int e = 0; e < 4; ++e) {
                        if (l == 0) { if (col_[e] < 100) npre[e] = nb_[e][(size_t)(s + 2) * BB * 100]; }
                        else if (col_[e] < H)
                            vcur[e] = aldu(pb_[e] + ((size_t)((s + 2) & (RD - 1)) * BB * RROW));
                    }
                }
            }
            if (tid == 448 && l > 0 && wantx)
                astu(cons_in, (unsigned)(s + 2));
        }
        __syncthreads();   // B2
    }
}
}  // namespace

extern "C" void kernel_launch(void* const* d_in, const int* in_sizes, int n_in,
                              void* d_out, int out_size, void* d_ws, size_t ws_size,
                              hipStream_t stream) {
    const float* noise = (const float*)d_in[0];
    const float* W_ih0 = (const float*)d_in[1];
    const float* W_hh0 = (const float*)d_in[2];
    const float* b_ih0 = (const float*)d_in[3];
    const float* b_hh0 = (const float*)d_in[4];
    const float* W_ih  = (const float*)d_in[5];
    const float* W_hh  = (const float*)d_in[6];
    const float* b_ih  = (const float*)d_in[7];
    const float* b_hh  = (const float*)d_in[8];

    // clear counters + rings (10 producer rings) each call — replay-safe
    const size_t clear_bytes = RING_OFF_B + (size_t)10 * RING_PER_L * sizeof(unsigned);
    hipMemsetAsync(d_ws, 0, clear_bytes, stream);

    unsigned* cnt = (unsigned*)d_ws;
    unsigned* ring = (unsigned*)((char*)d_ws + RING_OFF_B);

    lstm_wave<<<dim3(NLAYER * RGN), dim3(NTHR), 0, stream>>>(
        noise, (float*)d_out, cnt, ring,
        W_ih0, W_hh0, b_ih0, b_hh0, W_ih, W_hh, b_ih, b_hh);
}

// Round 14
// 1287.051 us; speedup vs baseline: 1.4456x; 1.4456x over previous
//
#include <hip/hip_runtime.h>
#include <cmath>

// R14: wavefront LSTM with MACRO-BATCHED consume (K=8).
// R9-R13 counters: WRITE_SIZE ~660-708MB == total ring-store bytes -> the
// relaxed agent-scope handoff stream bypasses L2; the per-step consume
// dependency (tag poll -> install -> MFMA) is the ~3700cyc/step gap vs R7's
// 2540cyc compute core. Stores never stall (fire-and-forget) -> keep per-step
// publish; batch the CONSUME: at each 8-step macro boundary issue all tagged
// loads at once (full MLP, one latency exposure), install to LDS x[8] buffer,
// then 8 substeps with zero IC interaction. Backpressure+consumed counters
// once per macro. Compute core + publish format: R11-validated, unchanged.
// Pipeline depth 512 + 10*8 = 592 effective steps.

namespace {
constexpr int H = 106, G4 = 424, SEQ = 512, BB = 256, KIN0 = 100;
constexpr int GST = 436;            // gates row stride (f32)
constexpr int NTHR = 896;           // 14 waves
constexpr int RGN = 16;             // rowgroups (16 rows each)
constexpr int NLAYER = 11;
constexpr int RD = 16;              // ring depth (steps); 2 macros
constexpr int REL = 56;             // u64 elements per ring row
constexpr int KMAC = 8;             // macro size (steps)
constexpr size_t CNT_STRIDE = 16;   // dwords per counter (64B)
constexpr size_t RING_OFF_B = 65536;
constexpr size_t RING_PER_L = (size_t)RD * BB * REL;   // u64 elements

using f16x8 = __attribute__((ext_vector_type(8))) _Float16;
using f32x4 = __attribute__((ext_vector_type(4))) float;
typedef unsigned long long u64;

__device__ __forceinline__ u64 ald(const u64* p) {
    return __hip_atomic_load(p, __ATOMIC_RELAXED, __HIP_MEMORY_SCOPE_AGENT);
}
__device__ __forceinline__ void ast(u64* p, u64 v) {
    __hip_atomic_store(p, v, __ATOMIC_RELAXED, __HIP_MEMORY_SCOPE_AGENT);
}
__device__ __forceinline__ unsigned aldu(const unsigned* p) {
    return __hip_atomic_load(p, __ATOMIC_RELAXED, __HIP_MEMORY_SCOPE_AGENT);
}
__device__ __forceinline__ void astu(unsigned* p, unsigned v) {
    __hip_atomic_store(p, v, __ATOMIC_RELAXED, __HIP_MEMORY_SCOPE_AGENT);
}
__device__ __forceinline__ void spinc(const unsigned* p, unsigned tgt) {
    while (aldu(p) < tgt) __builtin_amdgcn_s_sleep(8);
}
__device__ __forceinline__ float fast_tanh(float x) {
    float t = __expf(2.0f * x);
    return 1.0f - 2.0f / (t + 1.0f);
}
__device__ __forceinline__ float act_gate(float g, bool istanh) {
    float s = istanh ? 2.0f * g : g;
    float r = 1.0f / (1.0f + __expf(-s));
    return istanh ? 2.0f * r - 1.0f : r;
}
__device__ __forceinline__ unsigned packh2(float a, float b) {
    unsigned lo = (unsigned)__builtin_bit_cast(unsigned short, (_Float16)a);
    unsigned hi = (unsigned)__builtin_bit_cast(unsigned short, (_Float16)b);
    return (hi << 16) | lo;
}

__global__ __launch_bounds__(NTHR)
__attribute__((amdgpu_waves_per_eu(4, 4)))
void lstm_wave(const float* __restrict__ noise,   // (512,256,100) f32
               float* __restrict__ yout,          // (512,256,106) f32
               unsigned* cnt, u64* ring,
               const float* __restrict__ W_ih0, const float* __restrict__ W_hh0,
               const float* __restrict__ b_ih0, const float* __restrict__ b_hh0,
               const float* __restrict__ W_ih,  const float* __restrict__ W_hh,
               const float* __restrict__ b_ih,  const float* __restrict__ b_hh)
{
    const int l = blockIdx.x / RGN;
    const int rg = blockIdx.x % RGN;
    const bool LAST = (l == NLAYER - 1);
    const int K_IN = (l == 0) ? KIN0 : H;

    const float* Wih = (l == 0) ? W_ih0 : W_ih + (size_t)(l - 1) * G4 * H;
    const float* Whh = (l == 0) ? W_hh0 : W_hh + (size_t)(l - 1) * G4 * H;
    const float* pbi = (l == 0) ? b_ih0 : b_ih + (size_t)(l - 1) * G4;
    const float* pbh = (l == 0) ? b_hh0 : b_hh + (size_t)(l - 1) * G4;

    unsigned* cons_my = cnt + (size_t)(l * RGN + rg) * CNT_STRIDE;
    unsigned* cons_in = cnt + (size_t)((l - 1) * RGN + rg) * CNT_STRIDE;
    u64* ring_in  = ring + (size_t)(l - 1) * RING_PER_L;
    u64* ring_out = ring + (size_t)l * RING_PER_L;

    // LDS: x bundle for a whole macro (8 substeps), h state, gates.
    __shared__ __align__(16) _Float16 sx[KMAC][16 * 136];  // 34.8 KB
    __shared__ __align__(16) _Float16 sh[16 * 136];        //  4.4 KB
    __shared__ float gl[16 * GST];                         // 27.9 KB

    const int tid = threadIdx.x;
    const int w = tid >> 6, lane = tid & 63;
    const int l16 = lane & 15, kg = lane >> 4;
    const int lm = tid / 56, ld = tid % 56;   // loader map (row, element)
    const int um = tid / 53, up = tid % 53;   // update map (row, H-pair)

    // ---- weights: 2 N-tiles/wave, 8 k-steps (validated R8-R13) ----
    f16x8 bf[2][8];
    float bias[2];
    #pragma unroll
    for (int t = 0; t < 2; ++t) {
        const int n = 16 * (2 * w + t) + l16;
        const bool valid = n < G4;
        const float* pwx = Wih + (size_t)(valid ? n : 0) * K_IN;
        const float* pwh = Whh + (size_t)(valid ? n : 0) * H;
        #pragma unroll
        for (int q = 0; q < 8; ++q) {
            f16x8 v;
            #pragma unroll
            for (int e = 0; e < 8; ++e) {
                const int k = 32 * q + 8 * kg + e;
                float f = 0.0f;
                if (valid) {
                    if (k < 128) { if (k < K_IN) f = pwx[k]; }
                    else { const int kh = k - 128; if (kh < H) f = pwh[kh]; }
                }
                v[e] = (_Float16)f;
            }
            bf[t][q] = v;
        }
        bias[t] = valid ? (pbi[n] + pbh[n]) : 0.0f;
    }

    // ---- init: zero sx (all slots) + sh ----
    for (int i = tid; i < KMAC * 1088 + 1088; i += NTHR) {
        if (i < KMAC * 1088) ((unsigned*)sx)[i] = 0;
        else ((unsigned*)sh)[i - KMAC * 1088] = 0;
    }
    float c0 = 0.0f, c1 = 0.0f;
    __syncthreads();

    for (int m = 0; m < SEQ / KMAC; ++m) {
        // ---- acquire: x bundle for steps 8m..8m+7 ----
        unsigned xw[KMAC] = {0, 0, 0, 0, 0, 0, 0, 0};
        if (l == 0) {
            if (ld < 50) {
                #pragma unroll
                for (int ss = 0; ss < KMAC; ++ss) {
                    const int s = KMAC * m + ss;
                    const float2 t = *(const float2*)(noise +
                        ((size_t)s * BB + rg * 16 + lm) * KIN0 + 2 * ld);
                    xw[ss] = packh2(t.x, t.y);
                }
            }
        } else {
            u64 v[KMAC];
            #pragma unroll
            for (int ss = 0; ss < KMAC; ++ss) {    // issue all loads (MLP)
                const int s = KMAC * m + ss;
                v[ss] = ald(ring_in + ((size_t)(s & (RD - 1)) * BB + rg * 16 + lm) * REL + ld);
            }
            #pragma unroll
            for (int ss = 0; ss < KMAC; ++ss) {    // verify tags
                const int s = KMAC * m + ss;
                const unsigned expt = (unsigned)(s + 1);
                const u64* pin = ring_in + ((size_t)(s & (RD - 1)) * BB + rg * 16 + lm) * REL + ld;
                u64 vv = v[ss];
                while ((unsigned)(vv >> 32) != expt) { __builtin_amdgcn_s_sleep(2); vv = ald(pin); }
                xw[ss] = (unsigned)vv;
            }
        }
        // producer backpressure, once per macro: slots for steps 8m..8m+7
        // overwrite steps 8m-16..8m-9 -> need cons >= 8m-8 (macro m-2 consumed)
        if (tid == 0 && !LAST && m >= 2) spinc(cons_my, (unsigned)(KMAC * m - 8));
        // install (cols 56..67 u32 of each row stay zero from init)
        if (l > 0 || ld < 50) {
            #pragma unroll
            for (int ss = 0; ss < KMAC; ++ss)
                ((unsigned*)sx)[ss * 1088 + lm * 68 + ld] = xw[ss];
        }
        __syncthreads();   // install done; acquire loads drained
        if (tid == 0 && l > 0) astu(cons_in, (unsigned)(KMAC * m + KMAC));

        // ---- 8 substeps, zero IC interaction on the consume side ----
        for (int ss = 0; ss < KMAC; ++ss) {
            const int s = KMAC * m + ss;
            // x-part + h-part MFMAs
            f32x4 acc[2] = {{0, 0, 0, 0}, {0, 0, 0, 0}};
            const _Float16* ax = &sx[ss][l16 * 136 + 8 * kg];
            #pragma unroll
            for (int q = 0; q < 4; ++q) {
                const f16x8 a = *(const f16x8*)(ax + 32 * q);
                acc[0] = __builtin_amdgcn_mfma_f32_16x16x32_f16(a, bf[0][q], acc[0], 0, 0, 0);
                acc[1] = __builtin_amdgcn_mfma_f32_16x16x32_f16(a, bf[1][q], acc[1], 0, 0, 0);
            }
            const _Float16* ah = &sh[l16 * 136 + 8 * kg];
            #pragma unroll
            for (int q = 4; q < 8; ++q) {
                const f16x8 a = *(const f16x8*)(ah + 32 * (q - 4));
                acc[0] = __builtin_amdgcn_mfma_f32_16x16x32_f16(a, bf[0][q], acc[0], 0, 0, 0);
                acc[1] = __builtin_amdgcn_mfma_f32_16x16x32_f16(a, bf[1][q], acc[1], 0, 0, 0);
            }
            // activation -> gl. C map: row=4*kg+r, col=l16 (validated).
            #pragma unroll
            for (int t = 0; t < 2; ++t) {
                const int n = 16 * (2 * w + t) + l16;
                if (n < G4) {
                    const bool istanh = (n >= 2 * H) && (n < 3 * H);
                    #pragma unroll
                    for (int r = 0; r < 4; ++r)
                        gl[(4 * kg + r) * GST + n] = act_gate(acc[t][r] + bias[t], istanh);
                }
            }
            __syncthreads();   // B1: gates ready; sh reads of this substep done

            // state update + publish (fire-and-forget tagged u64 stores)
            if (tid < 848) {
                const float* gm = gl + um * GST;
                const float2 vi = *(const float2*)(gm + 2 * up);
                const float2 vf = *(const float2*)(gm + H + 2 * up);
                const float2 vg = *(const float2*)(gm + 2 * H + 2 * up);
                const float2 vo = *(const float2*)(gm + 3 * H + 2 * up);
                c0 = fmaf(vf.x, c0, vi.x * vg.x);
                c1 = fmaf(vf.y, c1, vi.y * vg.y);
                const float h0 = vo.x * fast_tanh(c0);
                const float h1 = vo.y * fast_tanh(c1);
                const unsigned hw = packh2(h0, h1);
                ((unsigned*)sh)[um * 68 + up] = hw;
                if (LAST) {
                    *(float2*)(yout + ((size_t)s * BB + rg * 16 + um) * H + 2 * up) =
                        make_float2(h0, h1);
                } else {
                    ast(ring_out + ((size_t)(s & (RD - 1)) * BB + rg * 16 + um) * REL + up,
                        ((u64)(unsigned)(s + 1) << 32) | hw);
                }
            } else if (!LAST) {   // pad elements 53..55 = 0, tagged
                const int t2 = tid - 848, mm = t2 / 3, dd = t2 % 3;
                ast(ring_out + ((size_t)(s & (RD - 1)) * BB + rg * 16 + mm) * REL + 53 + dd,
                    (u64)(unsigned)(s + 1) << 32);
            }
            __syncthreads();   // B2: h_s visible for next substep
        }
    }
}
}  // namespace

extern "C" void kernel_launch(void* const* d_in, const int* in_sizes, int n_in,
                              void* d_out, int out_size, void* d_ws, size_t ws_size,
                              hipStream_t stream) {
    const float* noise = (const float*)d_in[0];
    const float* W_ih0 = (const float*)d_in[1];
    const float* W_hh0 = (const float*)d_in[2];
    const float* b_ih0 = (const float*)d_in[3];
    const float* b_hh0 = (const float*)d_in[4];
    const float* W_ih  = (const float*)d_in[5];
    const float* W_hh  = (const float*)d_in[6];
    const float* b_ih  = (const float*)d_in[7];
    const float* b_hh  = (const float*)d_in[8];

    // clear counters + rings each call (replay-safe)
    const size_t clear_bytes = RING_OFF_B + (size_t)10 * RING_PER_L * sizeof(u64);
    hipMemsetAsync(d_ws, 0, clear_bytes, stream);

    unsigned* cnt = (unsigned*)d_ws;
    u64* ring = (u64*)((char*)d_ws + RING_OFF_B);

    lstm_wave<<<dim3(NLAYER * RGN), dim3(NTHR), 0, stream>>>(
        noise, (float*)d_out, cnt, ring,
        W_ih0, W_hh0, b_ih0, b_hh0, W_ih, W_hh, b_ih, b_hh);
}